// Round 6
// baseline (130.235 us; speedup 1.0000x reference)
//
#include <hip/hip_runtime.h>

// Problem constants (fixed by setup_inputs in the reference)
#define B_  8
#define T_  2048
#define D_  1024
#define H_  8
#define S_  128
#define NSPAN (B_ * S_)
#define NBLK  256      // persistent workers, 1/CU (LDS-limited), dynamic queue

// --------------------------------------------------------------------------
// R13 = R12 (v5) resubmitted verbatim: R12's bench died on container
// acquisition ("MI355X container failed twice") — no kernel evidence was
// produced. Pre-resubmit audit: barriers block-uniform (have/havenext from
// s_slot after syncthreads), queue slots double-buffered with 2 barriers
// between rewrite and last read, no OOB (kwr max 8188; begins/ends guarded;
// rows <= begin+31 <= 2046), VGPR est ~118 <= 128 cap.
//
// v5 design (from R12):
//  - Fixed: 2 x 256 MiB unconditional ws poison fills = 82.4 us (R8/R9).
//  - v1/v3/v4 all ~30-33 us controllable despite different scheduling =>
//    shared bottleneck: the dot read 32 KB of kw from LDS PER ROW
//    (32 ds_read_b128/row/wave) + phase3 LDS => ~16 us serialized LDS pipe
//    vs 10.7 us HBM floor.
//  - v5 inverts operands: kw lives in REGISTERS (wave pair: p=0 holds
//    heads 0-3, p=1 heads 4-7; 64 VGPR), rows live in LDS (needed for
//    phase3 anyway). Each wave loads HALF its row from HBM, stashes,
//    reads partner's half: dot LDS cost 32 reads -> 4W+4R per row.
//    Phase3: 256 threads x float4. LDS pipe ~4.4 us << HBM 10.7 us.
//  - Pop issued at loop TOP into alternating LDS slot; 2-slot register
//    prefetch of next span covers the softmax/phase3 HBM gap.
//  - Spill check: WRITE_SIZE ~4.5 MB expected (R9's spill showed 150 MB).
//  - LDS: rowbuf 128 KB + wts 1 KB -> 1 block/CU, 16 waves.
// --------------------------------------------------------------------------

__global__ void init_counter(unsigned int* __restrict__ c) { *c = 0u; }

__global__ __launch_bounds__(1024, 4) void span_pool_v5(
    const float* __restrict__ feat,    // [B*T, D]
    const int* __restrict__ begins,    // [B*S]
    const int* __restrict__ ends,      // [B*S]
    const float* __restrict__ kw,      // [H, D]
    const float* __restrict__ kb,      // [H]
    float* __restrict__ out,           // [B*S, D]
    unsigned int* __restrict__ counter)
{
    const int tid  = threadIdx.x;
    const int wv   = tid >> 6;              // 0..15
    const int lane = tid & 63;
    const int w    = wv >> 1;               // row-slot base 0..7
    const int p    = wv & 1;                // head-half: 0 -> heads 0-3, 1 -> 4-7
    const int coff = p * 512 + lane * 4;    // my half-row columns

    __shared__ __align__(16) float rowbuf[32 * D_];   // 128 KB span rows
    __shared__ __align__(16) float wts[32 * H_];      // 1 KB logits->weights
    __shared__ unsigned int s_slot[2];

    // kw for my 4 heads, full D, in registers (statically indexed only)
    float4 kwr[4][4];
#pragma unroll
    for (int h = 0; h < 4; ++h)
#pragma unroll
        for (int c = 0; c < 4; ++c)
            kwr[h][c] = *(const float4*)(kw + (size_t)(4*p + h) * D_ + c * 256 + lane * 4);

    const float kbq = kb[4*p + (lane & 3)];

    // dot one row-slot: my half (ra,rb) from regs, other half from rowbuf
    auto dot_slot = [&](int r, float4 ra, float4 rb) {
        const float* rbo = &rowbuf[r * D_ + (p ? 0 : 512) + lane * 4];
        float4 fo0 = *(const float4*)(rbo);
        float4 fo1 = *(const float4*)(rbo + 256);
        const float4 f0 = p ? fo0 : ra;
        const float4 f1 = p ? fo1 : rb;
        const float4 f2 = p ? ra  : fo0;
        const float4 f3 = p ? rb  : fo1;
        float acc[4];
#pragma unroll
        for (int h = 0; h < 4; ++h) {
            acc[h] = f0.x*kwr[h][0].x + f0.y*kwr[h][0].y + f0.z*kwr[h][0].z + f0.w*kwr[h][0].w
                   + f1.x*kwr[h][1].x + f1.y*kwr[h][1].y + f1.z*kwr[h][1].z + f1.w*kwr[h][1].w
                   + f2.x*kwr[h][2].x + f2.y*kwr[h][2].y + f2.z*kwr[h][2].z + f2.w*kwr[h][2].w
                   + f3.x*kwr[h][3].x + f3.y*kwr[h][3].y + f3.z*kwr[h][3].z + f3.w*kwr[h][3].w;
        }
        // value-compacting reduce (4 values over lane bits 0..1, then xor 4..32)
        const bool hb = lane & 1;
        float mine  = hb ? acc[1] : acc[0];
        float other = hb ? acc[0] : acc[1];
        float t0 = mine + __shfl_xor(other, 1, 64);
        mine  = hb ? acc[3] : acc[2];
        other = hb ? acc[2] : acc[3];
        float t1 = mine + __shfl_xor(other, 1, 64);
        const bool hb2 = (lane >> 1) & 1;
        mine  = hb2 ? t1 : t0;
        other = hb2 ? t0 : t1;
        float r0 = mine + __shfl_xor(other, 2, 64);
        r0 += __shfl_xor(r0,  4, 64);
        r0 += __shfl_xor(r0,  8, 64);
        r0 += __shfl_xor(r0, 16, 64);
        r0 += __shfl_xor(r0, 32, 64);
        if (lane < 4) wts[r * H_ + 4*p + lane] = r0 + kbq;   // head 4p+lane
    };

    // ---- prologue: pop first span, prefetch slots 0,1 (rows w, w+8)
    if (tid == 0) s_slot[0] = atomicAdd(counter, 1u);
    __syncthreads();
    int s = (int)s_slot[0];
    bool have = (s < NSPAN);
    int width = 0; size_t row0 = 0;
    float4 pfa0, pfa1, pfb0, pfb1;
    if (have) {
        const int bg = begins[s];
        width = ends[s] - bg;               // 1..32, rows always in-bounds
        row0  = (size_t)(s >> 7) * T_ + bg;
        if (w < width) {
            const float* fr = feat + (row0 + w) * D_ + coff;
            pfa0 = *(const float4*)(fr); pfa1 = *(const float4*)(fr + 256);
        }
        if (w + 8 < width) {
            const float* fr = feat + (row0 + w + 8) * D_ + coff;
            pfb0 = *(const float4*)(fr); pfb1 = *(const float4*)(fr + 256);
        }
    }

    int it = 0;
    while (have) {
        // pop NEXT span at loop top: atomic latency hides under sweep1+dot
        if (tid == 0) s_slot[(it + 1) & 1] = atomicAdd(counter, 1u);

        // ---- sweep1: issue far-slot loads, stash all my row-halves
        float4 g2a, g2b, g3a, g3b;
        const bool v2 = (w + 16) < width, v3 = (w + 24) < width;
        if (v2) { const float* fr = feat + (row0 + w + 16) * D_ + coff;
                  g2a = *(const float4*)(fr); g2b = *(const float4*)(fr + 256); }
        if (v3) { const float* fr = feat + (row0 + w + 24) * D_ + coff;
                  g3a = *(const float4*)(fr); g3b = *(const float4*)(fr + 256); }
        if (w < width) {
            float* rb = &rowbuf[w * D_ + coff];
            *(float4*)(rb) = pfa0; *(float4*)(rb + 256) = pfa1;
        }
        if (w + 8 < width) {
            float* rb = &rowbuf[(w + 8) * D_ + coff];
            *(float4*)(rb) = pfb0; *(float4*)(rb + 256) = pfb1;
        }
        if (v2) { float* rb = &rowbuf[(w + 16) * D_ + coff];
                  *(float4*)(rb) = g2a; *(float4*)(rb + 256) = g2b; }
        if (v3) { float* rb = &rowbuf[(w + 24) * D_ + coff];
                  *(float4*)(rb) = g3a; *(float4*)(rb + 256) = g3b; }
        __syncthreads();                    // (B1) rowbuf complete

        // ---- sweep2: dot my 4 row-slots (kw from regs, other half from LDS)
        if (w < width)      dot_slot(w,      pfa0, pfa1);
        if (w + 8 < width)  dot_slot(w + 8,  pfb0, pfb1);
        if (v2)             dot_slot(w + 16, g2a, g2b);
        if (v3)             dot_slot(w + 24, g3a, g3b);
        __syncthreads();                    // (B2) wts complete; next pop visible

        // ---- read next span; issue its prefetch NOW (flies over softmax+p3)
        const int snext = (int)s_slot[(it + 1) & 1];
        const bool havenext = (snext < NSPAN);
        int width_n = 0; size_t row0_n = 0;
        if (havenext) {
            const int bg = begins[snext];
            width_n = ends[snext] - bg;
            row0_n  = (size_t)(snext >> 7) * T_ + bg;
            if (w < width_n) {
                const float* fr = feat + (row0_n + w) * D_ + coff;
                pfa0 = *(const float4*)(fr); pfa1 = *(const float4*)(fr + 256);
            }
            if (w + 8 < width_n) {
                const float* fr = feat + (row0_n + w + 8) * D_ + coff;
                pfb0 = *(const float4*)(fr); pfb1 = *(const float4*)(fr + 256);
            }
        }

        // ---- wave-0 register softmax over wts (proven, in place)
        if (tid < 64) {
            float4 lv = *(const float4*)&wts[lane * 4];
            const int w8 = width * H_;
            float v0 = (4 * lane + 0 < w8) ? lv.x : -1e30f;
            float v1 = (4 * lane + 1 < w8) ? lv.y : -1e30f;
            float v2s = (4 * lane + 2 < w8) ? lv.z : -1e30f;
            float v3s = (4 * lane + 3 < w8) ? lv.w : -1e30f;

            float m0 = v0, m1 = v1, m2 = v2s, m3 = v3s;
#pragma unroll
            for (int off = 2; off <= 32; off <<= 1) {
                m0 = fmaxf(m0, __shfl_xor(m0, off, 64));
                m1 = fmaxf(m1, __shfl_xor(m1, off, 64));
                m2 = fmaxf(m2, __shfl_xor(m2, off, 64));
                m3 = fmaxf(m3, __shfl_xor(m3, off, 64));
            }
            float e0 = __expf(v0 - m0);     // masked -> exactly 0
            float e1 = __expf(v1 - m1);
            float e2 = __expf(v2s - m2);
            float e3 = __expf(v3s - m3);
            float s0 = e0, s1 = e1, s2 = e2, s3 = e3;
#pragma unroll
            for (int off = 2; off <= 32; off <<= 1) {
                s0 += __shfl_xor(s0, off, 64);
                s1 += __shfl_xor(s1, off, 64);
                s2 += __shfl_xor(s2, off, 64);
                s3 += __shfl_xor(s3, off, 64);
            }
            *(float4*)&wts[lane * 4] =
                make_float4(e0 / s0, e1 / s1, e2 / s2, e3 / s3);
        }
        __syncthreads();                    // (C) weights ready

        // ---- phase 3: threads 0..255, thread t owns cols 4t..4t+3 (one head)
        if (tid < 256) {
            const int ha = tid >> 5;        // head of cols 4t..4t+3
            float4 a = make_float4(0.f, 0.f, 0.f, 0.f);
#pragma unroll 4
            for (int k = 0; k < width; ++k) {
                const float4 rv = *(const float4*)&rowbuf[k * D_ + tid * 4];
                const float wt = wts[k * H_ + ha];
                a.x += wt * rv.x; a.y += wt * rv.y;
                a.z += wt * rv.z; a.w += wt * rv.w;
            }
            *(float4*)(out + (size_t)s * D_ + tid * 4) = a;
        }
        __syncthreads();                    // (A) rowbuf/wts free for next stash

        s = snext; have = havenext; width = width_n; row0 = row0_n; ++it;
    }
}

extern "C" void kernel_launch(void* const* d_in, const int* in_sizes, int n_in,
                              void* d_out, int out_size, void* d_ws, size_t ws_size,
                              hipStream_t stream) {
    const float* feat   = (const float*)d_in[0];   // features f32 [B,T,D]
    const int*   begins = (const int*)d_in[1];     // int32 [B,S]
    const int*   ends   = (const int*)d_in[2];     // int32 [B,S]
    const float* kw     = (const float*)d_in[3];   // key_w f32 [H,D]
    const float* kb     = (const float*)d_in[4];   // key_b f32 [H]
    float*       out    = (float*)d_out;           // f32 [B*S, D]
    unsigned int* counter = (unsigned int*)d_ws;   // 4 B of ws (poison unconditional)

    init_counter<<<1, 1, 0, stream>>>(counter);
    span_pool_v5<<<NBLK, 1024, 0, stream>>>(feat, begins, ends, kw, kb, out, counter);
}